// Round 11
// baseline (101.906 us; speedup 1.0000x reference)
//
#include <hip/hip_runtime.h>
#include <hip/hip_bf16.h>

// ContrastiveLoss (NT-Xent): B=2048, D=256, T=0.5
// loss = mean_i [ -2*dot(zh_i, zh_pos(i)) + log( sum_j exp(2*dot(zh_i, zh_j)) - e^2 ) ]
// v8 (from v7, 78.2us): k_sim was ~18us vs ~3us compute floor -- all 1056 blocks
// staged in one lock-step burst (no stage/compute overlap, 16x B re-read).
//  (1) k_sim: 528 blocks x 2 tiles, double-buffered B staging (T3 2-phase):
//      stage B0+A -> drain+barrier -> issue B1 -> compute tile0 (B1 latency hides
//      under MFMA/exp2) -> barrier -> compute tile1. A loaded ONCE per block
//      (consecutive tiles always share a 128-row panel: panel tile-counts even).
//      LDS 66KB, __launch_bounds__(256,2); XCD swizzle chunk 66 (528=8*66).
//  (2) ONE operand array z2 = sqrt(2*log2e) * zhat; A and B both read it ->
//      dot(z2_i,z2_j) = 2*log2e*sim -> exp2 = bare v_exp_f32. Halves k_norm
//      writes and k_sim L2 footprint (2MB, ~1MB/XCD after swizzle).
//  (3) k_loss reads only written slots (Prow jc>=2*panel(i); Pcol ib<panel(i);
//      the two ranges exactly partition all j) -> no Pall zeroing anywhere.
// Collision-free partial-sum stores (no global atomics in k_sim) kept from v6/v7.

typedef __attribute__((ext_vector_type(8))) short short8;
typedef __attribute__((ext_vector_type(4))) float float4v;

#define NROWS 4096
#define DIM 256
#define NB 2048
#define TEMP_INV 2.0f
#define SQSCALE 1.6986475601f  // sqrt(2*log2(e)); product of two = 2.88539008
#define NBLK 528               // 2 consecutive upper-tri 128x64 tiles per block

static __device__ __forceinline__ unsigned short f2bf_rne(float f) {
    unsigned int x = __float_as_uint(f);
    unsigned int r = x + 0x7FFFu + ((x >> 16) & 1u);
    return (unsigned short)(r >> 16);
}

// K1: normalize pair (p, p+NB) -> z2 (bf16 * sqrt(2log2e)); pos-dot pd[p]; zero out.
// grid 512 x 256.
__global__ __launch_bounds__(256) void k_norm(const float* __restrict__ zi,
                                              const float* __restrict__ zj,
                                              unsigned short* __restrict__ z2,
                                              float* __restrict__ pd,
                                              float* __restrict__ out) {
    if (blockIdx.x == 0 && threadIdx.x == 0) *out = 0.0f;
    int wave = threadIdx.x >> 6, lane = threadIdx.x & 63;
    int p = blockIdx.x * 4 + wave;  // pair index: rows p and p+NB
    float4 vi = *(const float4*)(zi + (size_t)p * DIM + lane * 4);
    float4 vj = *(const float4*)(zj + (size_t)p * DIM + lane * 4);
    float ssi = vi.x * vi.x + vi.y * vi.y + vi.z * vi.z + vi.w * vi.w;
    float ssj = vj.x * vj.x + vj.y * vj.y + vj.z * vj.z + vj.w * vj.w;
    float dij = vi.x * vj.x + vi.y * vj.y + vi.z * vj.z + vi.w * vj.w;
    #pragma unroll
    for (int off = 32; off > 0; off >>= 1) {
        ssi += __shfl_xor(ssi, off);
        ssj += __shfl_xor(ssj, off);
        dij += __shfl_xor(dij, off);
    }
    float si = 1.0f / fmaxf(sqrtf(ssi), 1e-12f);
    float sj = 1.0f / fmaxf(sqrtf(ssj), 1e-12f);
    float ki = si * SQSCALE, kj = sj * SQSCALE;
    ushort4 a2, b2;
    a2.x = f2bf_rne(vi.x * ki); a2.y = f2bf_rne(vi.y * ki);
    a2.z = f2bf_rne(vi.z * ki); a2.w = f2bf_rne(vi.w * ki);
    b2.x = f2bf_rne(vj.x * kj); b2.y = f2bf_rne(vj.y * kj);
    b2.z = f2bf_rne(vj.z * kj); b2.w = f2bf_rne(vj.w * kj);
    *(ushort4*)(z2 + (size_t)p * DIM + lane * 4) = a2;
    *(ushort4*)(z2 + (size_t)(p + NB) * DIM + lane * 4) = b2;
    if (lane == 0) pd[p] = dij * si * sj;
}

// K2: two consecutive 128x64 tiles (same 128-row panel), double-buffered B.
// Tile decode: ib in [0,32), jc in [2*ib, 64); do_col iff jc >= 2*ib+2.
__global__ __launch_bounds__(256, 2) void k_sim(const unsigned short* __restrict__ z2,
                                                float* __restrict__ Prow,
                                                float* __restrict__ Pcol) {
    __shared__ __attribute__((aligned(1024))) short Bs[2][64 * 256];  // 64 KB dbuf
    __shared__ float cs[2][64];

    // XCD-chunked swizzle (bijective: 528 = 8 * 66)
    int bid = blockIdx.x;
    int swb = (bid & 7) * 66 + (bid >> 3);
    int t0 = swb * 2;  // even global tile index; t0,t0+1 share a row panel
    int rem = t0, ib = 0;
    while (rem >= 64 - 2 * ib) { rem -= 64 - 2 * ib; ib++; }
    int jc0 = 2 * ib + rem;       // within-panel offset 'rem' is even
    int jc1 = jc0 + 1;            // still inside panel (panel tile-count even)
    bool do_col0 = (jc0 >= 2 * ib + 2);
    bool do_col1 = (jc1 >= 2 * ib + 2);

    int tid = threadIdx.x, wave = tid >> 6, lane = tid & 63;
    int m = lane & 15, q = lane >> 4;
    const short* zs = (const short*)z2;
    int ibase = ib * 128 + wave * 32;

    if (tid < 128) cs[tid >> 6][tid & 63] = 0.0f;

    // Staging: 64 B-rows (512B each) of strip jb into LDS buffer bufp.
    // global_load_lds writes 1024B=2 rows linearly (lane -> base+lane*16);
    // source slot pre-swizzled (slot ^ (row&7)); read side applies same XOR.
    int s_slot = lane & 31;    // 16B slot within row
    int rhalf = lane >> 5;     // 0 or 1
    #define STAGE(jb, bufp)                                                          \
        _Pragma("unroll")                                                            \
        for (int c = 0; c < 8; c++) {                                                \
            int r = wave * 16 + c * 2 + rhalf;                                       \
            const short* gsrc = zs + (size_t)((jb)*64 + r) * DIM +                   \
                                ((s_slot ^ (r & 7)) * 8);                            \
            short* ldst = (bufp) + (wave * 16 + c * 2) * 256;                        \
            __builtin_amdgcn_global_load_lds(                                        \
                (const __attribute__((address_space(1))) unsigned int*)gsrc,         \
                (__attribute__((address_space(3))) unsigned int*)ldst, 16, 0, 0);    \
        }

    STAGE(jc0, &Bs[0][0]);

    // A fragments: A[m][k], m = lane&15, k = q*8 + t (verified 16x16x32 layout);
    // loaded ONCE -- both tiles share the row panel.
    short8 A[2][8];
    #pragma unroll
    for (int t = 0; t < 2; t++) {
        const short* arow = zs + (size_t)(ibase + t * 16 + m) * DIM + q * 8;
        #pragma unroll
        for (int kk = 0; kk < 8; kk++) A[t][kk] = *(const short8*)(arow + kk * 32);
    }

    asm volatile("s_waitcnt vmcnt(0)" ::: "memory");
    __syncthreads();

    // Issue next strip NOW; its latency hides under tile-0 compute.
    STAGE(jc1, &Bs[1][0]);

    int swz = m & 7;
    #pragma unroll
    for (int ph = 0; ph < 2; ph++) {
        const short* bsb = (ph == 0) ? &Bs[0][0] : &Bs[1][0];
        int jc = (ph == 0) ? jc0 : jc1;
        bool do_col = (ph == 0) ? do_col0 : do_col1;

        float rowacc[2][4] = {{0.f, 0.f, 0.f, 0.f}, {0.f, 0.f, 0.f, 0.f}};
        #pragma unroll
        for (int jt = 0; jt < 4; jt++) {
            const short* brow = bsb + (jt * 16 + m) * 256;
            float4v c0 = {0.f, 0.f, 0.f, 0.f};
            float4v c1 = {0.f, 0.f, 0.f, 0.f};
            #pragma unroll
            for (int kk = 0; kk < 8; kk++) {
                short8 b = *(const short8*)(brow + (((q + 4 * kk) ^ swz) * 8));
                c0 = __builtin_amdgcn_mfma_f32_16x16x32_bf16(A[0][kk], b, c0, 0, 0, 0);
                c1 = __builtin_amdgcn_mfma_f32_16x16x32_bf16(A[1][kk], b, c1, 0, 0, 0);
            }
            float csum = 0.0f;
            #pragma unroll
            for (int r = 0; r < 4; r++) {
                float e0 = __builtin_exp2f(c0[r]);
                float e1 = __builtin_exp2f(c1[r]);
                rowacc[0][r] += e0; rowacc[1][r] += e1;
                csum += e0 + e1;
            }
            if (do_col) {
                csum += __shfl_xor(csum, 16);
                csum += __shfl_xor(csum, 32);
                if (lane < 16) atomicAdd(&cs[ph][jt * 16 + m], csum);
            }
        }
        // row sums: reduce over 16 column-lanes, plain store Prow[jc][row]
        #pragma unroll
        for (int t = 0; t < 2; t++) {
            #pragma unroll
            for (int r = 0; r < 4; r++) {
                float s = rowacc[t][r];
                s += __shfl_xor(s, 1);
                s += __shfl_xor(s, 2);
                s += __shfl_xor(s, 4);
                s += __shfl_xor(s, 8);
                if (m == 0) Prow[jc * NROWS + ibase + t * 16 + q * 4 + r] = s;
            }
        }
        if (ph == 0) {
            __syncthreads();  // drains B1 (landed during compute) + orders cs[0]
            if (do_col0 && tid < 64) Pcol[ib * NROWS + jc0 * 64 + tid] = cs[0][tid];
        } else if (do_col1) {
            __syncthreads();  // orders cs[1]
            if (tid < 64) Pcol[ib * NROWS + jc1 * 64 + tid] = cs[1][tid];
        }
    }
    #undef STAGE
}

// K3: S_i = sum over VALID slots only (no zero-init needed):
//   Prow planes jc in [2*panel(i), 64)  (i as row)
//   Pcol planes ib in [0, panel(i))     (i as column; strictly-upper tiles)
// These exactly partition all j. loss = mean log(S_i - e^2) - 2*pd[i%NB].
// grid 16 x 256, one row per thread, coalesced plane reads.
__global__ __launch_bounds__(256) void k_loss(const float* __restrict__ Prow,
                                              const float* __restrict__ Pcol,
                                              const float* __restrict__ pd,
                                              float* __restrict__ out) {
    __shared__ float red[4];
    int wave = threadIdx.x >> 6, lane = threadIdx.x & 63;
    int i = blockIdx.x * 256 + threadIdx.x;
    int ibp = i >> 7;  // row panel of i
    float s = 0.0f;
    for (int jc = 2 * ibp; jc < 64; jc++) s += Prow[jc * NROWS + i];
    for (int ib = 0; ib < ibp; ib++) s += Pcol[ib * NROWS + i];
    const float E2 = 7.38905609893065f;  // exp(sim_ii) = e^2
    float term = logf(s - E2) - TEMP_INV * pd[i & (NB - 1)];
    #pragma unroll
    for (int off = 32; off > 0; off >>= 1) term += __shfl_xor(term, off);
    if (lane == 0) red[wave] = term;
    __syncthreads();
    if (threadIdx.x == 0) {
        float t = (red[0] + red[1] + red[2] + red[3]) * (1.0f / NROWS);
        atomicAdd(out, t);
    }
}

extern "C" void kernel_launch(void* const* d_in, const int* in_sizes, int n_in,
                              void* d_out, int out_size, void* d_ws, size_t ws_size,
                              hipStream_t stream) {
    const float* zi = (const float*)d_in[0];
    const float* zj = (const float*)d_in[1];
    float* out = (float*)d_out;
    char* ws = (char*)d_ws;
    unsigned short* z2 = (unsigned short*)ws;                  // 2 MB bf16 * sqrt(2log2e)
    float* Prow = (float*)(ws + 2 * 1024 * 1024);              // [64][4096] = 1 MB
    float* Pcol = (float*)(ws + 3 * 1024 * 1024);              // [32][4096] = 512 KB
    float* pd   = (float*)(ws + 3 * 1024 * 1024 + 512 * 1024); // 8 KB pos dots

    hipLaunchKernelGGL(k_norm, dim3(512), dim3(256), 0, stream, zi, zj, z2, pd, out);
    hipLaunchKernelGGL(k_sim, dim3(NBLK), dim3(256), 0, stream, z2, Prow, Pcol);
    hipLaunchKernelGGL(k_loss, dim3(16), dim3(256), 0, stream, Prow, Pcol, pd, out);
}

// Round 13
// 78.098 us; speedup vs baseline: 1.3049x; 1.3049x over previous
//
#include <hip/hip_runtime.h>
#include <hip/hip_bf16.h>

// ContrastiveLoss (NT-Xent): B=2048, D=256, T=0.5
// loss = mean_i [ -2*dot(zh_i, zh_pos(i)) + log( sum_j exp(2*dot(zh_i, zh_j)) - e^2 ) ]
// v9 = v7 (78.2us, best) with k_sim-internal changes ONLY. Evidence (v1/v5/v8):
// every multi-tile-per-block serial structure costs ~+20us; keep 1-tile blocks.
//  (1) own-quarter-first: each wave stages its own 16 B-rows; vmcnt is per-wave,
//      so after draining its OWN loads it computes jt==wave (reads only its own
//      staged rows) BEFORE the block barrier -> ~1/4 of compute hides under
//      staging skew, barrier leaves the critical path.
//  (2) LDS col-sum atomics -> per-wave plain-store partials csw[4][64], combined
//      once after the final barrier (no atomic serialization, no init hazard).
// Kept from v7: 1056 one-tile blocks, __launch_bounds__(256,4) (4 blocks/CU),
// XCD-chunked bijective swizzle (1056=8*132), global_load_lds w=16 staging with
// XOR-swizzled source + swizzled ds_read, collision-free Prow/Pcol partial-sum
// stores, zb2 pre-scaled by 2*log2(e) so exp(2*sim)=exp2(dot) -> bare v_exp_f32.

typedef __attribute__((ext_vector_type(8))) short short8;
typedef __attribute__((ext_vector_type(4))) float float4v;

#define NROWS 4096
#define DIM 256
#define NB 2048
#define TEMP_INV 2.0f
#define SCALE 2.8853900817779268f  // 2*log2(e)
#define NTILES 1056  // sum_{ib=0}^{31} (64 - 2*ib) upper-triangular 128x64 tiles

static __device__ __forceinline__ unsigned short f2bf_rne(float f) {
    unsigned int x = __float_as_uint(f);
    unsigned int r = x + 0x7FFFu + ((x >> 16) & 1u);
    return (unsigned short)(r >> 16);
}

// K1: normalize pair (p, p+NB); zero Pall (1.5 MB) and out. grid 512 x 256.
__global__ __launch_bounds__(256) void k_norm(const float* __restrict__ zi,
                                              const float* __restrict__ zj,
                                              unsigned short* __restrict__ zb,
                                              unsigned short* __restrict__ zb2,
                                              float* __restrict__ pd,
                                              float4* __restrict__ pzero,
                                              float* __restrict__ out) {
    if (blockIdx.x == 0 && threadIdx.x == 0) *out = 0.0f;
    // zero Pall = 96 planes x 4096 floats = 98304 float4s across 131072 threads
    {
        int g = blockIdx.x * 256 + threadIdx.x;
        if (g < 98304) {
            float4 z; z.x = 0.f; z.y = 0.f; z.z = 0.f; z.w = 0.f;
            pzero[g] = z;
        }
    }
    int wave = threadIdx.x >> 6, lane = threadIdx.x & 63;
    int p = blockIdx.x * 4 + wave;  // pair index: rows p and p+NB
    float4 vi = *(const float4*)(zi + (size_t)p * DIM + lane * 4);
    float4 vj = *(const float4*)(zj + (size_t)p * DIM + lane * 4);
    float ssi = vi.x * vi.x + vi.y * vi.y + vi.z * vi.z + vi.w * vi.w;
    float ssj = vj.x * vj.x + vj.y * vj.y + vj.z * vj.z + vj.w * vj.w;
    float dij = vi.x * vj.x + vi.y * vj.y + vi.z * vj.z + vi.w * vj.w;
    #pragma unroll
    for (int off = 32; off > 0; off >>= 1) {
        ssi += __shfl_xor(ssi, off);
        ssj += __shfl_xor(ssj, off);
        dij += __shfl_xor(dij, off);
    }
    float si = 1.0f / fmaxf(sqrtf(ssi), 1e-12f);
    float sj = 1.0f / fmaxf(sqrtf(ssj), 1e-12f);
    ushort4 a, b;
    a.x = f2bf_rne(vi.x * si); a.y = f2bf_rne(vi.y * si);
    a.z = f2bf_rne(vi.z * si); a.w = f2bf_rne(vi.w * si);
    b.x = f2bf_rne(vj.x * sj); b.y = f2bf_rne(vj.y * sj);
    b.z = f2bf_rne(vj.z * sj); b.w = f2bf_rne(vj.w * sj);
    *(ushort4*)(zb + (size_t)p * DIM + lane * 4) = a;
    *(ushort4*)(zb + (size_t)(p + NB) * DIM + lane * 4) = b;
    float ki = si * SCALE, kj = sj * SCALE;
    ushort4 a2, b2;
    a2.x = f2bf_rne(vi.x * ki); a2.y = f2bf_rne(vi.y * ki);
    a2.z = f2bf_rne(vi.z * ki); a2.w = f2bf_rne(vi.w * ki);
    b2.x = f2bf_rne(vj.x * kj); b2.y = f2bf_rne(vj.y * kj);
    b2.z = f2bf_rne(vj.z * kj); b2.w = f2bf_rne(vj.w * kj);
    *(ushort4*)(zb2 + (size_t)p * DIM + lane * 4) = a2;
    *(ushort4*)(zb2 + (size_t)(p + NB) * DIM + lane * 4) = b2;
    if (lane == 0) pd[p] = dij * si * sj;
}

// K2: one upper-triangular 128x64 exp2-tile per block; partial-sum stores.
// Tile decode: ib in [0,32), jc in [2*ib, 64).
__global__ __launch_bounds__(256, 4) void k_sim(const unsigned short* __restrict__ zb,
                                                const unsigned short* __restrict__ zb2,
                                                float* __restrict__ Prow,
                                                float* __restrict__ Pcol) {
    __shared__ __attribute__((aligned(1024))) short Bs[64 * 256];  // 32 KB linear rows
    __shared__ float csw[4][64];  // per-wave column partials (plain stores)
    // XCD-chunked swizzle (bijective: 1056 % 8 == 0, chunk = 132): consecutive
    // tiles (sharing an A row-panel) land on the same XCD's L2.
    int bid = blockIdx.x;
    int swb = (bid & 7) * 132 + (bid >> 3);
    int rem = swb, ib = 0;
    while (rem >= 64 - 2 * ib) { rem -= 64 - 2 * ib; ib++; }
    int jc = 2 * ib + rem;
    bool do_col = (jc >= 2 * ib + 2);

    int tid = threadIdx.x, wave = tid >> 6, lane = tid & 63;
    int m = lane & 15, q = lane >> 4;
    const short* zsB = (const short*)zb;
    const short* zsA = (const short*)zb2;
    int ibase = ib * 128 + wave * 32;
    int jbase = jc * 64;

    // Async-stage 64 B-rows (512B each) into LDS. Each global_load_lds writes
    // 1024B = 2 rows linearly (lane -> base + lane*16). Source slot pre-swizzled
    // (slot ^ (row&7)); read side applies the same XOR.
    // NOTE: wave w stages exactly rows [w*16, w*16+16) -- own-quarter property.
    {
        int s = lane & 31;      // 16B slot within row
        int rhalf = lane >> 5;  // 0 or 1
        #pragma unroll
        for (int c = 0; c < 8; c++) {
            int r = wave * 16 + c * 2 + rhalf;  // local row (own 16-row band)
            const short* gsrc = zsB + (size_t)(jbase + r) * DIM + ((s ^ (r & 7)) * 8);
            short* ldst = &Bs[(wave * 16 + c * 2) * 256];  // wave-uniform base
            __builtin_amdgcn_global_load_lds(
                (const __attribute__((address_space(1))) unsigned int*)gsrc,
                (__attribute__((address_space(3))) unsigned int*)ldst,
                16, 0, 0);
        }
    }

    // A fragments: A[m][k], m = lane&15, k = q*8 + t  (verified 16x16x32 layout)
    short8 A[2][8];
    #pragma unroll
    for (int t = 0; t < 2; t++) {
        const short* arow = zsA + (size_t)(ibase + t * 16 + m) * DIM + q * 8;
        #pragma unroll
        for (int kk = 0; kk < 8; kk++) A[t][kk] = *(const short8*)(arow + kk * 32);
    }

    // Drain OWN loads only (vmcnt is per-wave); own-quarter compute can start
    // before the block barrier -- other waves' staging completes meanwhile.
    asm volatile("s_waitcnt vmcnt(0)" ::: "memory");

    float rowacc[2][4] = {{0.f, 0.f, 0.f, 0.f}, {0.f, 0.f, 0.f, 0.f}};
    int swz = m & 7;

    #pragma unroll
    for (int step = 0; step < 4; step++) {
        int jt = (wave + step) & 3;  // step 0: own staged rows (jt == wave)
        const short* brow = &Bs[(jt * 16 + m) * 256];
        float4v c0 = {0.f, 0.f, 0.f, 0.f};
        float4v c1 = {0.f, 0.f, 0.f, 0.f};
        #pragma unroll
        for (int kk = 0; kk < 8; kk++) {
            short8 b = *(const short8*)(brow + (((q + 4 * kk) ^ swz) * 8));
            c0 = __builtin_amdgcn_mfma_f32_16x16x32_bf16(A[0][kk], b, c0, 0, 0, 0);
            c1 = __builtin_amdgcn_mfma_f32_16x16x32_bf16(A[1][kk], b, c1, 0, 0, 0);
        }
        float csum = 0.0f;
        #pragma unroll
        for (int r = 0; r < 4; r++) {
            float e0 = __builtin_exp2f(c0[r]);
            float e1 = __builtin_exp2f(c1[r]);
            rowacc[0][r] += e0; rowacc[1][r] += e1;
            csum += e0 + e1;
        }
        if (do_col) {
            // column jt*16 + m: this wave's 32-row partial, plain store
            csum += __shfl_xor(csum, 16);
            csum += __shfl_xor(csum, 32);
            if (lane < 16) csw[wave][jt * 16 + m] = csum;
        }
        if (step == 0) __syncthreads();  // all waves' staging complete after this
    }

    // row sums: reduce over 16 column-lanes, plain store into Prow[jc][row]
    #pragma unroll
    for (int t = 0; t < 2; t++) {
        #pragma unroll
        for (int r = 0; r < 4; r++) {
            float s = rowacc[t][r];
            s += __shfl_xor(s, 1);
            s += __shfl_xor(s, 2);
            s += __shfl_xor(s, 4);
            s += __shfl_xor(s, 8);
            if (m == 0) Prow[jc * NROWS + ibase + t * 16 + q * 4 + r] = s;
        }
    }
    if (do_col) {
        __syncthreads();  // all csw writes visible
        if (tid < 64) {
            float c = csw[0][tid] + csw[1][tid] + csw[2][tid] + csw[3][tid];
            Pcol[ib * NROWS + jbase + tid] = c;
        }
    }
}

// K3: S_i = sum of 96 contiguous partial planes (Pall = Prow planes 0..63,
// Pcol planes 64..95); loss = mean log(S_i - e^2) - 2*pd[i%NB]. grid 64 x 256:
// block handles 64 rows; 4 plane-quarters per row combined in LDS.
__global__ __launch_bounds__(256) void k_loss(const float* __restrict__ Pall,
                                              const float* __restrict__ pd,
                                              float* __restrict__ out) {
    __shared__ float red2[4][64];
    int tid = threadIdx.x;
    int t = tid & 63, quarter = tid >> 6;
    int row = blockIdx.x * 64 + t;
    float s = 0.0f;
    #pragma unroll
    for (int k = 0; k < 24; k++) {
        int p = quarter * 24 + k;
        s += Pall[(size_t)p * NROWS + row];
    }
    red2[quarter][t] = s;
    __syncthreads();
    if (tid < 64) {
        float tot = red2[0][t] + red2[1][t] + red2[2][t] + red2[3][t];
        const float E2 = 7.38905609893065f;  // exp(sim_ii) = e^2
        float term = logf(tot - E2) - TEMP_INV * pd[row & (NB - 1)];
        #pragma unroll
        for (int off = 32; off > 0; off >>= 1) term += __shfl_xor(term, off);
        if (t == 0) atomicAdd(out, term * (1.0f / NROWS));
    }
}

extern "C" void kernel_launch(void* const* d_in, const int* in_sizes, int n_in,
                              void* d_out, int out_size, void* d_ws, size_t ws_size,
                              hipStream_t stream) {
    const float* zi = (const float*)d_in[0];
    const float* zj = (const float*)d_in[1];
    float* out = (float*)d_out;
    char* ws = (char*)d_ws;
    unsigned short* zb  = (unsigned short*)ws;                          // 2 MB bf16 normalized
    unsigned short* zb2 = (unsigned short*)(ws + 2 * 1024 * 1024);      // 2 MB bf16 * 2log2e
    float* Pall = (float*)(ws + 4 * 1024 * 1024);                       // 96 planes x 4096 = 1.5 MB
    float* Prow = Pall;                                                 // planes 0..63 (by jc)
    float* Pcol = Pall + 64 * NROWS;                                    // planes 64..95 (by ib)
    float* pd   = (float*)(ws + 5 * 1024 * 1024 + 512 * 1024);          // 8 KB pos dots

    hipLaunchKernelGGL(k_norm, dim3(512), dim3(256), 0, stream,
                       zi, zj, zb, zb2, pd, (float4*)Pall, out);
    hipLaunchKernelGGL(k_sim, dim3(NTILES), dim3(256), 0, stream, zb, zb2, Prow, Pcol);
    hipLaunchKernelGGL(k_loss, dim3(64), dim3(256), 0, stream, Pall, pd, out);
}